// Round 7
// baseline (3167.953 us; speedup 1.0000x reference)
//
#include <hip/hip_runtime.h>
#include <cstdint>

#define Bb 64
#define Tt 4096
#define Dd 67
#define Hh 128
#define CH 16            // scan z-chunk: 16 steps x 512 n x 2B = 16 KB
#define NCH (Tt/CH)

typedef _Float16 f16;
typedef _Float16 half8 __attribute__((ext_vector_type(8)));
typedef _Float16 half2v __attribute__((ext_vector_type(2)));
typedef float f32x4 __attribute__((ext_vector_type(4)));

#define MFMA16(A,B,C) __builtin_amdgcn_mfma_f32_16x16x32_f16((A),(B),(C),0,0,0)

static __device__ __forceinline__ float fast_rcp(float x){ return __builtin_amdgcn_rcpf(x); }
static __device__ __forceinline__ float fast_ex2(float x){ return __builtin_amdgcn_exp2f(x); }
static __device__ __forceinline__ float rlane(float v, int l){
  return __builtin_bit_cast(float, __builtin_amdgcn_readlane(__builtin_bit_cast(int, v), l));
}
#define L2E  1.442695041f
#define L2E2 2.885390082f

// LDS-visibility barrier WITHOUT vmcnt drain: global loads/stores stay in
// flight across it.
#define SYNC() do { asm volatile("s_waitcnt lgkmcnt(0)" ::: "memory"); \
                    __builtin_amdgcn_s_barrier(); } while(0)

union U2 { uint2 u; f16 h[4]; };
union U1 { unsigned u; f16 h[2]; };
union H8 { half8 v; half2v p[4]; };

__device__ __forceinline__ void red2(float& s, float& q){
#pragma unroll
  for (int off = 32; off; off >>= 1){ s += __shfl_xor(s, off); q += __shfl_xor(q, off); }
}

// ---------------------------------------------------------------------------
// Stage A: LN(67) -> MFMA proj -> LN(128)+SiLU -> MFMA GEMM2 -> z fp16 to
// d_ws in scan layout [b][t][512], zoff(j,g)=(j>>5)*128+(j&15)*8+((j>>4)&1)*4+g.
// (unchanged, verified)
// ---------------------------------------------------------------------------
__global__ __launch_bounds__(512, 2)
void stage_a(const float* __restrict__ x,
             const float* __restrict__ g_in, const float* __restrict__ b_in,
             const float* __restrict__ proj_w, const float* __restrict__ proj_b,
             const float* __restrict__ g_p, const float* __restrict__ b_p,
             const float* __restrict__ w_ff1, const float* __restrict__ bi_ff1,
             const float* __restrict__ w_ff2, const float* __restrict__ bi_ff2,
             const float* __restrict__ w_ta,  const float* __restrict__ bi_ta,
             const float* __restrict__ w_tb,  const float* __restrict__ bi_tb,
             f16* __restrict__ zx)
{
  __shared__ __align__(16) f16   xn_s[16*104];
  __shared__ __align__(16) float fpre_s[16*132];
  __shared__ __align__(16) f16   feat_s[16*136];

  const int tid  = threadIdx.x;
  const int wv   = tid >> 6;
  const int lane = tid & 63;
  const int q    = lane >> 4;
  const int l16  = lane & 15;
  const int jq   = 16*wv + 4*q;

  const float* Wg[4] = { w_ff1, w_ff2, w_ta, w_tb };
  const float* Bg[4] = { bi_ff1, bi_ff2, bi_ta, bi_tb };

  half8 aW1[3];
#pragma unroll
  for (int c = 0; c < 3; ++c)
#pragma unroll
    for (int i = 0; i < 8; ++i){
      int k = 32*c + 8*q + i;
      aW1[c][i] = (k < Dd) ? (f16)proj_w[k*Hh + (16*wv + l16)] : (f16)0.f;
    }
  half8 aW2[4][4];
  f32x4 bias2[4];
#pragma unroll
  for (int g = 0; g < 4; ++g){
    const float* wp = Wg[g];
    const int jc = 16*wv + l16;
#pragma unroll
    for (int c = 0; c < 4; ++c)
#pragma unroll
      for (int i = 0; i < 8; ++i){
        int k = 32*c + 8*q + i;
        aW2[g][c][i] = (f16)wp[k*Hh + jc];
      }
    bias2[g] = *(const f32x4*)(Bg[g] + jq);
  }
  const float gi0 = g_in[lane], bi0 = b_in[lane];
  const float gi1 = (lane < 3) ? g_in[64+lane] : 0.f;
  const float bi1 = (lane < 3) ? b_in[64+lane] : 0.f;
  const float gp0 = g_p[lane],  bp0 = b_p[lane];
  const float gp1 = g_p[64+lane], bp1 = b_p[64+lane];
  const float pb0 = proj_b[lane], pb1 = proj_b[64+lane];

  for (int idx = tid; idx < 16*104; idx += 512)
    if ((idx % 104) >= Dd) xn_s[idx] = (f16)0.f;
  __syncthreads();

  const int wg   = blockIdx.x;
  const int b    = wg >> 2;
  const int t0wg = (wg & 3) * 1024;

  for (int it = 0; it < 64; ++it){
    const int tl0 = t0wg + it*16;
#pragma unroll
    for (int hf = 0; hf < 2; ++hf){
      const int ts = wv + 8*hf;
      const float* xr = x + (size_t)(b*Tt + tl0 + ts) * Dd;
      float v0 = xr[lane];
      float v1 = (lane < 3) ? xr[64+lane] : 0.f;
      float s = v0 + v1, qq = v0*v0 + v1*v1;
      red2(s, qq);
      float mu = s * (1.0f/Dd);
      float rstd = rsqrtf(qq * (1.0f/Dd) - mu*mu + 1e-5f);
      xn_s[ts*104 + lane] = (f16)((v0 - mu)*rstd*gi0 + bi0);
      if (lane < 3) xn_s[ts*104 + 64 + lane] = (f16)((v1 - mu)*rstd*gi1 + bi1);
    }
    __syncthreads();
    {
      f32x4 acc = {0.f, 0.f, 0.f, 0.f};
#pragma unroll
      for (int c = 0; c < 3; ++c){
        half8 bf = *(const half8*)(xn_s + l16*104 + 32*c + 8*q);
        acc = MFMA16(aW1[c], bf, acc);
      }
      *(f32x4*)(fpre_s + l16*132 + jq) = acc;
    }
    __syncthreads();
#pragma unroll
    for (int hf = 0; hf < 2; ++hf){
      const int ts = wv + 8*hf;
      float v0 = fpre_s[ts*132 + lane]      + pb0;
      float v1 = fpre_s[ts*132 + 64 + lane] + pb1;
      float s = v0 + v1, qq = v0*v0 + v1*v1;
      red2(s, qq);
      float mu = s * (1.0f/Hh);
      float rstd = rsqrtf(qq * (1.0f/Hh) - mu*mu + 1e-5f);
      float f0 = (v0 - mu)*rstd*gp0 + bp0;
      float f1 = (v1 - mu)*rstd*gp1 + bp1;
      f0 *= fast_rcp(1.0f + fast_ex2(-L2E*f0));
      f1 *= fast_rcp(1.0f + fast_ex2(-L2E*f1));
      feat_s[ts*136 + lane]      = (f16)f0;
      feat_s[ts*136 + 64 + lane] = (f16)f1;
    }
    __syncthreads();
    {
      half8 bf2[4];
#pragma unroll
      for (int c = 0; c < 4; ++c)
        bf2[c] = *(const half8*)(feat_s + l16*136 + 32*c + 8*q);
      const size_t trow = (size_t)(b*Tt + tl0 + l16) * 512;
      f32x4 accs2[4];
#pragma unroll
      for (int g = 0; g < 4; ++g){
        f32x4 acc = bias2[g];
#pragma unroll
        for (int c = 0; c < 4; ++c)
          acc = MFMA16(aW2[g][c], bf2[c], acc);
        accs2[g] = acc;
      }
      // scan layout store: j = 16wv+4q+r -> [w=wv>>1][l=4q+r][s=wv&1][g]
#pragma unroll
      for (int r = 0; r < 4; ++r){
        U2 u;
#pragma unroll
        for (int g = 0; g < 4; ++g) u.h[g] = (f16)accs2[g][r];
        const int zoff = ((wv>>1)*128) + ((4*q + r)*8) + ((wv&1)*4);
        *(uint2*)(zx + trow + zoff) = u.u;
      }
    }
    __syncthreads();
  }
}

// ---------------------------------------------------------------------------
// Scan v12 = v11 shell (staging/SYNC/prefetch/dump identical) with the
// matvec moved from MFMA to v_dot2_f32_f16 (zero M-waste):
//   lane (q,l16), wave w8: j = 16*w8+l16, K-slice k in [32q, 32q+32).
//   64 fdot2/lane (4 gates x 16 pairs, f32 accum) -> shfl_xor(16,32) reduce
//   over q -> + z -> cell (q-redundant, q==0 writes hist). MFMA count: 0.
// ---------------------------------------------------------------------------
__global__ __launch_bounds__(512, 1)
void scan_k(f16* __restrict__ zx, const float* __restrict__ dt,
            const float* __restrict__ w_ff1, const float* __restrict__ w_ff2,
            const float* __restrict__ w_ta,  const float* __restrict__ w_tb)
{
  __shared__ __align__(16) f16 zbuf[2][CH*512];  // 2 x 16 KB
  __shared__ __align__(16) f16 hist[CH][Hh];     // 4 KB ring of h [16][128]

  const int tid  = threadIdx.x;
  const int w8   = tid >> 6;        // 0..7: j = 16*w8 + l16
  const int lane = tid & 63;
  const int q    = lane >> 4;       // K-slice selector
  const int l16  = lane & 15;
  const int b    = blockIdx.x;

  const float* Wg[4] = { w_ff1, w_ff2, w_ta, w_tb };

  // per-lane weight column: W_g[128 + 32q + 2p + {0,1}][j], packed f16 pairs
  half2v wcol[4][16];
  {
    const int jc = 16*w8 + l16;
#pragma unroll
    for (int g = 0; g < 4; ++g){
      const float* wp = Wg[g];
#pragma unroll
      for (int p = 0; p < 16; ++p){
        const int k = 128 + 32*q + 2*p;
        half2v w2; w2[0] = (f16)wp[k*Hh + jc]; w2[1] = (f16)wp[(k+1)*Hh + jc];
        wcol[g][p] = w2;
      }
    }
  }

  // zero hist ring (slot 15 must be 0 for t=0): 512 thr x 8B = 4 KB
  ((float2*)hist)[tid] = make_float2(0.f, 0.f);

  f16* zg = zx + (size_t)b*Tt*512;
  const float4* zg4 = (const float4*)zg;         // chunk = 1024 float4

  // prologue: chunk0 -> regs -> zbuf[0]; chunk1 -> regs; dt chunk0 -> reg
  float4 rz[2];
  rz[0] = zg4[tid]; rz[1] = zg4[512 + tid];
  ((float4*)zbuf[0])[tid] = rz[0]; ((float4*)zbuf[0])[512 + tid] = rz[1];
  rz[0] = zg4[1024 + tid]; rz[1] = zg4[1536 + tid];
  float dtcur = dt[(size_t)b*Tt + l16] * 10.0f;
  __syncthreads();

  // lane's z slot (f16 elems) in a step row: j=16w8+l16 ->
  // (j>>5)*128 + (j&15)*8 + ((j>>4)&1)*4  (+g)
  const int zoff2 = (w8>>1)*128 + l16*8 + (w8&1)*4;

  for (int c = 0; c < NCH; ++c){
    const int cur = c & 1, nxt = cur ^ 1;
    ((float4*)zbuf[nxt])[tid] = rz[0];
    ((float4*)zbuf[nxt])[512 + tid] = rz[1];
    if (c + 2 < NCH){
      const float4* src = zg4 + (size_t)(c+2)*1024;
      rz[0] = src[tid]; rz[1] = src[512 + tid];
    }
    float dtnxt = dtcur;
    if (c + 1 < NCH) dtnxt = dt[(size_t)b*Tt + (c+1)*CH + l16] * 10.0f;
    const f16* zch = zbuf[cur];

    // zv pipeline prologue: step-0 z (zbuf[cur] written LAST chunk, visible)
    uint2 zv = *(const uint2*)(zch + zoff2);

#pragma unroll
    for (int st = 0; st < CH; ++st){
      const int slotR = (st + 15) & 15;
      // h k-slice [32q, 32q+32): 4 x b128, 2-way-broadcast (conflict-free)
      const f16* hp = &hist[slotR][32*q];
      H8 hv[4];
      hv[0].v = *(const half8*)(hp);
      hv[1].v = *(const half8*)(hp + 8);
      hv[2].v = *(const half8*)(hp + 16);
      hv[3].v = *(const half8*)(hp + 24);
      U2 uz; uz.u = zv;
      const float dtt = rlane(dtcur, st);

      // 64 fdot2: 4 indep accumulator chains (one per gate), f32 accum
      float a0 = 0.f, a1 = 0.f, a2 = 0.f, a3 = 0.f;
#pragma unroll
      for (int cc = 0; cc < 4; ++cc)
#pragma unroll
        for (int p = 0; p < 4; ++p){
          const half2v h2 = hv[cc].p[p];
          const int pi = 4*cc + p;
          a0 = __builtin_amdgcn_fdot2(wcol[0][pi], h2, a0, false);
          a1 = __builtin_amdgcn_fdot2(wcol[1][pi], h2, a1, false);
          a2 = __builtin_amdgcn_fdot2(wcol[2][pi], h2, a2, false);
          a3 = __builtin_amdgcn_fdot2(wcol[3][pi], h2, a3, false);
        }

      // prefetch next step's z (zbuf[cur] stable within chunk) before barrier
      if (st + 1 < CH) zv = *(const uint2*)(zch + (st+1)*512 + zoff2);

      // reduce partial sums across q (lanes 16,32 apart)
      a0 += __shfl_xor(a0, 16); a1 += __shfl_xor(a1, 16);
      a2 += __shfl_xor(a2, 16); a3 += __shfl_xor(a3, 16);
      a0 += __shfl_xor(a0, 32); a1 += __shfl_xor(a1, 32);
      a2 += __shfl_xor(a2, 32); a3 += __shfl_xor(a3, 32);

      // cell for j = 16w8+l16 (q-redundant; q==0 writes)
      float p0 = a0 + (float)uz.h[0];
      float p1 = a1 + (float)uz.h[1];
      float p2 = a2 + (float)uz.h[2];
      float p3 = a3 + (float)uz.h[3];
      float gpre = __builtin_fmaf(p2, dtt, p3);
      float g_ = fast_rcp(fast_ex2(-L2E*gpre) + 1.0f);
      float u_ = fast_rcp(fast_ex2(L2E2*p0) + 1.0f);   // (1-tanh)/2
      float v_ = fast_rcp(fast_ex2(L2E2*p1) + 1.0f);
      float a_ = __builtin_fmaf(-2.0f, u_, 1.0f);
      float hn = __builtin_fmaf(2.0f*g_, u_ - v_, a_);
      if (q == 0)
        hist[st][16*w8 + l16] = (f16)hn;
      SYNC();
    }
    // dump h ring into consumed z region: h[t] -> zg[t*512 + 0..127]
    {
      const uint2 hv2 = ((const uint2*)hist)[tid];
      *(uint2*)(zg + ((size_t)(c*CH + (tid >> 5)))*512 + (size_t)(tid & 31)*4) = hv2;
    }
    SYNC();
    dtcur = dtnxt;
  }
}

// ---------------------------------------------------------------------------
// Head: out[tok] = h[tok] . head_w + head_b (h fp16 from dumped region).
// ---------------------------------------------------------------------------
__global__ __launch_bounds__(256, 4)
void head_k(const f16* __restrict__ zx, const float* __restrict__ head_w,
            const float* __restrict__ head_b, float* __restrict__ out)
{
  const int tok  = (blockIdx.x << 2) + (threadIdx.x >> 6);
  const int lane = threadIdx.x & 63;
  U1 cv; cv.u = *(const unsigned*)(zx + (size_t)tok*512 + 2*lane);
  float s = (float)cv.h[0]*head_w[2*lane] + (float)cv.h[1]*head_w[2*lane+1];
#pragma unroll
  for (int off = 32; off; off >>= 1) s += __shfl_xor(s, off);
  if (lane == 0) out[tok] = s + head_b[0];
}

extern "C" void kernel_launch(void* const* d_in, const int* in_sizes, int n_in,
                              void* d_out, int out_size, void* d_ws, size_t ws_size,
                              hipStream_t stream)
{
  const float* x       = (const float*)d_in[0];
  const float* dt      = (const float*)d_in[1];
  const float* ln_in_g = (const float*)d_in[2];
  const float* ln_in_b = (const float*)d_in[3];
  const float* proj_w  = (const float*)d_in[4];
  const float* proj_b  = (const float*)d_in[5];
  const float* ln_p_g  = (const float*)d_in[6];
  const float* ln_p_b  = (const float*)d_in[7];
  const float* ff1_w   = (const float*)d_in[8];
  const float* ff1_b   = (const float*)d_in[9];
  const float* ff2_w   = (const float*)d_in[10];
  const float* ff2_b   = (const float*)d_in[11];
  const float* ta_w    = (const float*)d_in[12];
  const float* ta_b    = (const float*)d_in[13];
  const float* tb_w    = (const float*)d_in[14];
  const float* tb_b    = (const float*)d_in[15];
  const float* head_w  = (const float*)d_in[16];
  const float* head_b  = (const float*)d_in[17];

  f16*   zx  = (f16*)d_ws;      // [b][t][512] fp16 = 256 MiB (z, then h)
  float* out = (float*)d_out;

  stage_a<<<dim3(256), dim3(512), 0, stream>>>(
      x, ln_in_g, ln_in_b, proj_w, proj_b, ln_p_g, ln_p_b,
      ff1_w, ff1_b, ff2_w, ff2_b, ta_w, ta_b, tb_w, tb_b, zx);

  scan_k<<<dim3(Bb), dim3(512), 0, stream>>>(
      zx, dt, ff1_w, ff2_w, ta_w, tb_w);

  head_k<<<dim3(Bb*Tt/4), dim3(256), 0, stream>>>(
      zx, head_w, head_b, out);
}

// Round 9
// 2237.884 us; speedup vs baseline: 1.4156x; 1.4156x over previous
//
#include <hip/hip_runtime.h>
#include <cstdint>

#define Bb 64
#define Tt 4096
#define Dd 67
#define Hh 128
#define CH 16            // scan z-chunk: 16 steps x 512 n x 2B = 16 KB
#define NCH (Tt/CH)

typedef _Float16 f16;
typedef _Float16 half8 __attribute__((ext_vector_type(8)));
typedef float f32x4 __attribute__((ext_vector_type(4)));

#define MFMA16(A,B,C) __builtin_amdgcn_mfma_f32_16x16x32_f16((A),(B),(C),0,0,0)

static __device__ __forceinline__ float fast_rcp(float x){ return __builtin_amdgcn_rcpf(x); }
static __device__ __forceinline__ float fast_ex2(float x){ return __builtin_amdgcn_exp2f(x); }
static __device__ __forceinline__ float rlane(float v, int l){
  return __builtin_bit_cast(float, __builtin_amdgcn_readlane(__builtin_bit_cast(int, v), l));
}
#define L2E  1.442695041f
#define L2E2 2.885390082f

// LDS-visibility barrier WITHOUT vmcnt drain: global loads/stores stay in
// flight across it.
#define SYNC() do { asm volatile("s_waitcnt lgkmcnt(0)" ::: "memory"); \
                    __builtin_amdgcn_s_barrier(); } while(0)

union U2 { uint2 u; f16 h[4]; };
union U1 { unsigned u; f16 h[2]; };

__device__ __forceinline__ void red2(float& s, float& q){
#pragma unroll
  for (int off = 32; off; off >>= 1){ s += __shfl_xor(s, off); q += __shfl_xor(q, off); }
}

// ---------------------------------------------------------------------------
// Stage A v13: LN(67) -> MFMA proj -> LN(128)+SiLU -> MFMA GEMM2 -> z fp16.
// Deltas vs verified v11 stage_a: (1) x loads software-pipelined one iter
// ahead (latency hides under iter body), (2) lgkm-only SYNC barriers so
// z-stores and x-prefetch loads fly across (no per-iter vmcnt(0) drains).
// Layout/math unchanged: zoff(j,g)=(j>>5)*128+(j&15)*8+((j>>4)&1)*4+g.
// ---------------------------------------------------------------------------
__global__ __launch_bounds__(512, 2)
void stage_a(const float* __restrict__ x,
             const float* __restrict__ g_in, const float* __restrict__ b_in,
             const float* __restrict__ proj_w, const float* __restrict__ proj_b,
             const float* __restrict__ g_p, const float* __restrict__ b_p,
             const float* __restrict__ w_ff1, const float* __restrict__ bi_ff1,
             const float* __restrict__ w_ff2, const float* __restrict__ bi_ff2,
             const float* __restrict__ w_ta,  const float* __restrict__ bi_ta,
             const float* __restrict__ w_tb,  const float* __restrict__ bi_tb,
             f16* __restrict__ zx)
{
  __shared__ __align__(16) f16   xn_s[16*104];
  __shared__ __align__(16) float fpre_s[16*132];
  __shared__ __align__(16) f16   feat_s[16*136];

  const int tid  = threadIdx.x;
  const int wv   = tid >> 6;
  const int lane = tid & 63;
  const int q    = lane >> 4;
  const int l16  = lane & 15;
  const int jq   = 16*wv + 4*q;

  const float* Wg[4] = { w_ff1, w_ff2, w_ta, w_tb };
  const float* Bg[4] = { bi_ff1, bi_ff2, bi_ta, bi_tb };

  half8 aW1[3];
#pragma unroll
  for (int c = 0; c < 3; ++c)
#pragma unroll
    for (int i = 0; i < 8; ++i){
      int k = 32*c + 8*q + i;
      aW1[c][i] = (k < Dd) ? (f16)proj_w[k*Hh + (16*wv + l16)] : (f16)0.f;
    }
  half8 aW2[4][4];
  f32x4 bias2[4];
#pragma unroll
  for (int g = 0; g < 4; ++g){
    const float* wp = Wg[g];
    const int jc = 16*wv + l16;
#pragma unroll
    for (int c = 0; c < 4; ++c)
#pragma unroll
      for (int i = 0; i < 8; ++i){
        int k = 32*c + 8*q + i;
        aW2[g][c][i] = (f16)wp[k*Hh + jc];
      }
    bias2[g] = *(const f32x4*)(Bg[g] + jq);
  }
  const float gi0 = g_in[lane], bi0 = b_in[lane];
  const float gi1 = (lane < 3) ? g_in[64+lane] : 0.f;
  const float bi1 = (lane < 3) ? b_in[64+lane] : 0.f;
  const float gp0 = g_p[lane],  bp0 = b_p[lane];
  const float gp1 = g_p[64+lane], bp1 = b_p[64+lane];
  const float pb0 = proj_b[lane], pb1 = proj_b[64+lane];

  for (int idx = tid; idx < 16*104; idx += 512)
    if ((idx % 104) >= Dd) xn_s[idx] = (f16)0.f;
  __syncthreads();

  const int wg   = blockIdx.x;
  const int b    = wg >> 2;
  const int t0wg = (wg & 3) * 1024;

  // x prefetch pipeline: iter 0 loads issued now
  float pv0[2], pv1[2];
#pragma unroll
  for (int hf = 0; hf < 2; ++hf){
    const float* xr = x + (size_t)(b*Tt + t0wg + wv + 8*hf) * Dd;
    pv0[hf] = xr[lane];
    pv1[hf] = (lane < 3) ? xr[64+lane] : 0.f;
  }

  for (int it = 0; it < 64; ++it){
    const int tl0 = t0wg + it*16;
    float cv0[2] = { pv0[0], pv0[1] };
    float cv1[2] = { pv1[0], pv1[1] };
    if (it + 1 < 64){
      const int tn = t0wg + (it+1)*16;
#pragma unroll
      for (int hf = 0; hf < 2; ++hf){
        const float* xr = x + (size_t)(b*Tt + tn + wv + 8*hf) * Dd;
        pv0[hf] = xr[lane];
        pv1[hf] = (lane < 3) ? xr[64+lane] : 0.f;
      }
    }
#pragma unroll
    for (int hf = 0; hf < 2; ++hf){
      const int ts = wv + 8*hf;
      float v0 = cv0[hf];
      float v1 = cv1[hf];
      float s = v0 + v1, qq = v0*v0 + v1*v1;
      red2(s, qq);
      float mu = s * (1.0f/Dd);
      float rstd = rsqrtf(qq * (1.0f/Dd) - mu*mu + 1e-5f);
      xn_s[ts*104 + lane] = (f16)((v0 - mu)*rstd*gi0 + bi0);
      if (lane < 3) xn_s[ts*104 + 64 + lane] = (f16)((v1 - mu)*rstd*gi1 + bi1);
    }
    SYNC();
    {
      f32x4 acc = {0.f, 0.f, 0.f, 0.f};
#pragma unroll
      for (int c = 0; c < 3; ++c){
        half8 bf = *(const half8*)(xn_s + l16*104 + 32*c + 8*q);
        acc = MFMA16(aW1[c], bf, acc);
      }
      *(f32x4*)(fpre_s + l16*132 + jq) = acc;
    }
    SYNC();
#pragma unroll
    for (int hf = 0; hf < 2; ++hf){
      const int ts = wv + 8*hf;
      float v0 = fpre_s[ts*132 + lane]      + pb0;
      float v1 = fpre_s[ts*132 + 64 + lane] + pb1;
      float s = v0 + v1, qq = v0*v0 + v1*v1;
      red2(s, qq);
      float mu = s * (1.0f/Hh);
      float rstd = rsqrtf(qq * (1.0f/Hh) - mu*mu + 1e-5f);
      float f0 = (v0 - mu)*rstd*gp0 + bp0;
      float f1 = (v1 - mu)*rstd*gp1 + bp1;
      f0 *= fast_rcp(1.0f + fast_ex2(-L2E*f0));
      f1 *= fast_rcp(1.0f + fast_ex2(-L2E*f1));
      feat_s[ts*136 + lane]      = (f16)f0;
      feat_s[ts*136 + 64 + lane] = (f16)f1;
    }
    SYNC();
    {
      half8 bf2[4];
#pragma unroll
      for (int c = 0; c < 4; ++c)
        bf2[c] = *(const half8*)(feat_s + l16*136 + 32*c + 8*q);
      const size_t trow = (size_t)(b*Tt + tl0 + l16) * 512;
      f32x4 accs2[4];
#pragma unroll
      for (int g = 0; g < 4; ++g){
        f32x4 acc = bias2[g];
#pragma unroll
        for (int c = 0; c < 4; ++c)
          acc = MFMA16(aW2[g][c], bf2[c], acc);
        accs2[g] = acc;
      }
      // scan layout store: j = 16wv+4q+r -> [w=wv>>1][l=4q+r][s=wv&1][g]
#pragma unroll
      for (int r = 0; r < 4; ++r){
        U2 u;
#pragma unroll
        for (int g = 0; g < 4; ++g) u.h[g] = (f16)accs2[g][r];
        const int zoff = ((wv>>1)*128) + ((4*q + r)*8) + ((wv&1)*4);
        *(uint2*)(zx + trow + zoff) = u.u;
      }
    }
    SYNC();
  }
}

// ---------------------------------------------------------------------------
// Scan v13 = v11 (verified 1899us) + 2 micro deltas:
//  (a) z folded into MFMA C-operand init (lane's C reg0 = z_j at row 4q):
//      deletes the post-MFMA z-add from the serial tail.
//  (b) s_setprio(1/0) around the MFMA cluster (T5): when the 2 waves/SIMD
//      drift into different phases, the MFMA-issuing wave wins arbitration.
// Everything else byte-identical to v11.
// ---------------------------------------------------------------------------
__global__ __launch_bounds__(512, 1)
void scan_k(f16* __restrict__ zx, const float* __restrict__ dt,
            const float* __restrict__ w_ff1, const float* __restrict__ w_ff2,
            const float* __restrict__ w_ta,  const float* __restrict__ w_tb)
{
  __shared__ __align__(16) f16 zbuf[2][CH*512];  // 2 x 16 KB
  __shared__ __align__(16) f16 hist[CH][Hh];     // 4 KB ring of h [16][128]

  const int tid  = threadIdx.x;
  const int w8   = tid >> 6;        // 0..7: j-range [16*w8, 16*w8+16)
  const int lane = tid & 63;
  const int q    = lane >> 4;
  const int l16  = lane & 15;
  const int b    = blockIdx.x;

  const float* Wg[4] = { w_ff1, w_ff2, w_ta, w_tb };

  // B operand = W_bot (k rows 128..255), col jc = 16*w8 + l16
  half8 bW[4][4];                   // [gate][kchunk]
#pragma unroll
  for (int g = 0; g < 4; ++g){
    const float* wp = Wg[g];
    const int jc = 16*w8 + l16;
#pragma unroll
    for (int c = 0; c < 4; ++c)
#pragma unroll
      for (int i = 0; i < 8; ++i)
        bW[g][c][i] = (f16)wp[(128 + 32*c + 8*q + i)*Hh + jc];
  }

  // zero hist ring (slot 15 must be 0 for t=0): 512 thr x 8B = 4 KB
  ((float2*)hist)[tid] = make_float2(0.f, 0.f);

  f16* zg = zx + (size_t)b*Tt*512;
  const float4* zg4 = (const float4*)zg;         // chunk = 1024 float4

  // prologue: chunk0 -> regs -> zbuf[0]; chunk1 -> regs; dt chunk0 -> reg
  float4 rz[2];
  rz[0] = zg4[tid]; rz[1] = zg4[512 + tid];
  ((float4*)zbuf[0])[tid] = rz[0]; ((float4*)zbuf[0])[512 + tid] = rz[1];
  rz[0] = zg4[1024 + tid]; rz[1] = zg4[1536 + tid];
  float dtcur = dt[(size_t)b*Tt + l16] * 10.0f;
  __syncthreads();

  const f32x4 zero4 = {0.f, 0.f, 0.f, 0.f};
  // lane's z slot (f16 elems) in a step row: j=16w8+l16 ->
  // (j>>5)*128 + (j&15)*8 + ((j>>4)&1)*4  (+g)
  const int zoff2 = (w8>>1)*128 + l16*8 + (w8&1)*4;

  for (int c = 0; c < NCH; ++c){
    const int cur = c & 1, nxt = cur ^ 1;
    ((float4*)zbuf[nxt])[tid] = rz[0];
    ((float4*)zbuf[nxt])[512 + tid] = rz[1];
    if (c + 2 < NCH){
      const float4* src = zg4 + (size_t)(c+2)*1024;
      rz[0] = src[tid]; rz[1] = src[512 + tid];
    }
    float dtnxt = dtcur;
    if (c + 1 < NCH) dtnxt = dt[(size_t)b*Tt + (c+1)*CH + l16] * 10.0f;
    const f16* zch = zbuf[cur];

    // zv pipeline prologue: step-0 z (zbuf[cur] written LAST chunk, visible)
    uint2 zv = *(const uint2*)(zch + zoff2);

#pragma unroll
    for (int st = 0; st < CH; ++st){
      const int slotR = (st + 15) & 15;
      // A operand: h broadcast (l16-independent), 4 x b128 — post-barrier path
      half8 af[4];
#pragma unroll
      for (int cc = 0; cc < 4; ++cc)
        af[cc] = *(const half8*)(&hist[slotR][32*cc + 8*q]);
      U2 uz; uz.u = zv;
      const float dtt = rlane(dtcur, st);

      // 8 indep depth-2 chains (4 gates x 2+2 K-split), 16 MFMA/wave.
      // z pre-loaded into pA's C reg0 (row 4q, col l16) — carried through.
      __builtin_amdgcn_s_setprio(1);
      f32x4 pA[4], pB[4];
#pragma unroll
      for (int g = 0; g < 4; ++g){
        f32x4 ci = zero4;
        ci[0] = (float)uz.h[g];
        pA[g] = MFMA16(af[0], bW[g][0], ci);
      }
#pragma unroll
      for (int g = 0; g < 4; ++g) pB[g] = MFMA16(af[2], bW[g][2], zero4);
#pragma unroll
      for (int g = 0; g < 4; ++g) pA[g] = MFMA16(af[1], bW[g][1], pA[g]);
#pragma unroll
      for (int g = 0; g < 4; ++g) pB[g] = MFMA16(af[3], bW[g][3], pB[g]);
      __builtin_amdgcn_s_setprio(0);

      // prefetch next step's z (zbuf[cur] stable within chunk) before barrier
      if (st + 1 < CH) zv = *(const uint2*)(zch + (st+1)*512 + zoff2);

      // cell for j = 16w8+l16 (q-redundant; q==0 writes)
      float p0 = pA[0][0] + pB[0][0];
      float p1 = pA[1][0] + pB[1][0];
      float p2 = pA[2][0] + pB[2][0];
      float p3 = pA[3][0] + pB[3][0];
      float gpre = __builtin_fmaf(p2, dtt, p3);
      float g_ = fast_rcp(fast_ex2(-L2E*gpre) + 1.0f);
      float u_ = fast_rcp(fast_ex2(L2E2*p0) + 1.0f);   // (1-tanh)/2
      float v_ = fast_rcp(fast_ex2(L2E2*p1) + 1.0f);
      float a_ = __builtin_fmaf(-2.0f, u_, 1.0f);
      float hn = __builtin_fmaf(2.0f*g_, u_ - v_, a_);
      if (q == 0)
        hist[st][16*w8 + l16] = (f16)hn;
      SYNC();
    }
    // dump h ring into consumed z region: h[t] -> zg[t*512 + 0..127]
    {
      const uint2 hv2 = ((const uint2*)hist)[tid];
      *(uint2*)(zg + ((size_t)(c*CH + (tid >> 5)))*512 + (size_t)(tid & 31)*4) = hv2;
    }
    SYNC();
    dtcur = dtnxt;
  }
}

// ---------------------------------------------------------------------------
// Head: out[tok] = h[tok] . head_w + head_b (h fp16 from dumped region).
// ---------------------------------------------------------------------------
__global__ __launch_bounds__(256, 4)
void head_k(const f16* __restrict__ zx, const float* __restrict__ head_w,
            const float* __restrict__ head_b, float* __restrict__ out)
{
  const int tok  = (blockIdx.x << 2) + (threadIdx.x >> 6);
  const int lane = threadIdx.x & 63;
  U1 cv; cv.u = *(const unsigned*)(zx + (size_t)tok*512 + 2*lane);
  float s = (float)cv.h[0]*head_w[2*lane] + (float)cv.h[1]*head_w[2*lane+1];
#pragma unroll
  for (int off = 32; off; off >>= 1) s += __shfl_xor(s, off);
  if (lane == 0) out[tok] = s + head_b[0];
}

extern "C" void kernel_launch(void* const* d_in, const int* in_sizes, int n_in,
                              void* d_out, int out_size, void* d_ws, size_t ws_size,
                              hipStream_t stream)
{
  const float* x       = (const float*)d_in[0];
  const float* dt      = (const float*)d_in[1];
  const float* ln_in_g = (const float*)d_in[2];
  const float* ln_in_b = (const float*)d_in[3];
  const float* proj_w  = (const float*)d_in[4];
  const float* proj_b  = (const float*)d_in[5];
  const float* ln_p_g  = (const float*)d_in[6];
  const float* ln_p_b  = (const float*)d_in[7];
  const float* ff1_w   = (const float*)d_in[8];
  const float* ff1_b   = (const float*)d_in[9];
  const float* ff2_w   = (const float*)d_in[10];
  const float* ff2_b   = (const float*)d_in[11];
  const float* ta_w    = (const float*)d_in[12];
  const float* ta_b    = (const float*)d_in[13];
  const float* tb_w    = (const float*)d_in[14];
  const float* tb_b    = (const float*)d_in[15];
  const float* head_w  = (const float*)d_in[16];
  const float* head_b  = (const float*)d_in[17];

  f16*   zx  = (f16*)d_ws;      // [b][t][512] fp16 = 256 MiB (z, then h)
  float* out = (float*)d_out;

  stage_a<<<dim3(256), dim3(512), 0, stream>>>(
      x, ln_in_g, ln_in_b, proj_w, proj_b, ln_p_g, ln_p_b,
      ff1_w, ff1_b, ff2_w, ff2_b, ta_w, ta_b, tb_w, tb_b, zx);

  scan_k<<<dim3(Bb), dim3(512), 0, stream>>>(
      zx, dt, ff1_w, ff2_w, ta_w, tb_w);

  head_k<<<dim3(Bb*Tt/4), dim3(256), 0, stream>>>(
      zx, head_w, head_b, out);
}

// Round 10
// 2192.453 us; speedup vs baseline: 1.4449x; 1.0207x over previous
//
#include <hip/hip_runtime.h>
#include <cstdint>

#define Bb 64
#define Tt 4096
#define Dd 67
#define Hh 128
#define CH 16            // scan z-chunk: 16 steps x 512 n x 2B = 16 KB
#define NCH (Tt/CH)

typedef _Float16 f16;
typedef _Float16 half8 __attribute__((ext_vector_type(8)));
typedef float f32x4 __attribute__((ext_vector_type(4)));

#define MFMA16(A,B,C) __builtin_amdgcn_mfma_f32_16x16x32_f16((A),(B),(C),0,0,0)

static __device__ __forceinline__ float fast_rcp(float x){ return __builtin_amdgcn_rcpf(x); }
static __device__ __forceinline__ float fast_ex2(float x){ return __builtin_amdgcn_exp2f(x); }
static __device__ __forceinline__ float rlane(float v, int l){
  return __builtin_bit_cast(float, __builtin_amdgcn_readlane(__builtin_bit_cast(int, v), l));
}
#define L2E  1.442695041f
#define L2E2 2.885390082f

// LDS-visibility barrier WITHOUT vmcnt drain: global loads/stores stay in
// flight across it.
#define SYNC() do { asm volatile("s_waitcnt lgkmcnt(0)" ::: "memory"); \
                    __builtin_amdgcn_s_barrier(); } while(0)

union U2 { uint2 u; f16 h[4]; };
union U1 { unsigned u; f16 h[2]; };

__device__ __forceinline__ void red2(float& s, float& q){
#pragma unroll
  for (int off = 32; off; off >>= 1){ s += __shfl_xor(s, off); q += __shfl_xor(q, off); }
}

// ---------------------------------------------------------------------------
// Stage A v14: v13 pipeline (x-prefetch + lgkm-only SYNC) at 512 blocks
// (2 blocks/CU): two independent iteration streams per CU overlap each
// other's barrier/shuffle/trans stalls. 32 iters x 512 tokens per block.
// Layout/math unchanged: zoff(j,g)=(j>>5)*128+(j&15)*8+((j>>4)&1)*4+g.
// ---------------------------------------------------------------------------
__global__ __launch_bounds__(512, 2)
void stage_a(const float* __restrict__ x,
             const float* __restrict__ g_in, const float* __restrict__ b_in,
             const float* __restrict__ proj_w, const float* __restrict__ proj_b,
             const float* __restrict__ g_p, const float* __restrict__ b_p,
             const float* __restrict__ w_ff1, const float* __restrict__ bi_ff1,
             const float* __restrict__ w_ff2, const float* __restrict__ bi_ff2,
             const float* __restrict__ w_ta,  const float* __restrict__ bi_ta,
             const float* __restrict__ w_tb,  const float* __restrict__ bi_tb,
             f16* __restrict__ zx)
{
  __shared__ __align__(16) f16   xn_s[16*104];
  __shared__ __align__(16) float fpre_s[16*132];
  __shared__ __align__(16) f16   feat_s[16*136];

  const int tid  = threadIdx.x;
  const int wv   = tid >> 6;
  const int lane = tid & 63;
  const int q    = lane >> 4;
  const int l16  = lane & 15;
  const int jq   = 16*wv + 4*q;

  const float* Wg[4] = { w_ff1, w_ff2, w_ta, w_tb };
  const float* Bg[4] = { bi_ff1, bi_ff2, bi_ta, bi_tb };

  half8 aW1[3];
#pragma unroll
  for (int c = 0; c < 3; ++c)
#pragma unroll
    for (int i = 0; i < 8; ++i){
      int k = 32*c + 8*q + i;
      aW1[c][i] = (k < Dd) ? (f16)proj_w[k*Hh + (16*wv + l16)] : (f16)0.f;
    }
  half8 aW2[4][4];
  f32x4 bias2[4];
#pragma unroll
  for (int g = 0; g < 4; ++g){
    const float* wp = Wg[g];
    const int jc = 16*wv + l16;
#pragma unroll
    for (int c = 0; c < 4; ++c)
#pragma unroll
      for (int i = 0; i < 8; ++i){
        int k = 32*c + 8*q + i;
        aW2[g][c][i] = (f16)wp[k*Hh + jc];
      }
    bias2[g] = *(const f32x4*)(Bg[g] + jq);
  }
  const float gi0 = g_in[lane], bi0 = b_in[lane];
  const float gi1 = (lane < 3) ? g_in[64+lane] : 0.f;
  const float bi1 = (lane < 3) ? b_in[64+lane] : 0.f;
  const float gp0 = g_p[lane],  bp0 = b_p[lane];
  const float gp1 = g_p[64+lane], bp1 = b_p[64+lane];
  const float pb0 = proj_b[lane], pb1 = proj_b[64+lane];

  for (int idx = tid; idx < 16*104; idx += 512)
    if ((idx % 104) >= Dd) xn_s[idx] = (f16)0.f;
  __syncthreads();

  const int wg   = blockIdx.x;
  const int b    = wg >> 3;
  const int t0wg = (wg & 7) * 512;

  // x prefetch pipeline: iter 0 loads issued now
  float pv0[2], pv1[2];
#pragma unroll
  for (int hf = 0; hf < 2; ++hf){
    const float* xr = x + (size_t)(b*Tt + t0wg + wv + 8*hf) * Dd;
    pv0[hf] = xr[lane];
    pv1[hf] = (lane < 3) ? xr[64+lane] : 0.f;
  }

  for (int it = 0; it < 32; ++it){
    const int tl0 = t0wg + it*16;
    float cv0[2] = { pv0[0], pv0[1] };
    float cv1[2] = { pv1[0], pv1[1] };
    if (it + 1 < 32){
      const int tn = t0wg + (it+1)*16;
#pragma unroll
      for (int hf = 0; hf < 2; ++hf){
        const float* xr = x + (size_t)(b*Tt + tn + wv + 8*hf) * Dd;
        pv0[hf] = xr[lane];
        pv1[hf] = (lane < 3) ? xr[64+lane] : 0.f;
      }
    }
#pragma unroll
    for (int hf = 0; hf < 2; ++hf){
      const int ts = wv + 8*hf;
      float v0 = cv0[hf];
      float v1 = cv1[hf];
      float s = v0 + v1, qq = v0*v0 + v1*v1;
      red2(s, qq);
      float mu = s * (1.0f/Dd);
      float rstd = rsqrtf(qq * (1.0f/Dd) - mu*mu + 1e-5f);
      xn_s[ts*104 + lane] = (f16)((v0 - mu)*rstd*gi0 + bi0);
      if (lane < 3) xn_s[ts*104 + 64 + lane] = (f16)((v1 - mu)*rstd*gi1 + bi1);
    }
    SYNC();
    {
      f32x4 acc = {0.f, 0.f, 0.f, 0.f};
#pragma unroll
      for (int c = 0; c < 3; ++c){
        half8 bf = *(const half8*)(xn_s + l16*104 + 32*c + 8*q);
        acc = MFMA16(aW1[c], bf, acc);
      }
      *(f32x4*)(fpre_s + l16*132 + jq) = acc;
    }
    SYNC();
#pragma unroll
    for (int hf = 0; hf < 2; ++hf){
      const int ts = wv + 8*hf;
      float v0 = fpre_s[ts*132 + lane]      + pb0;
      float v1 = fpre_s[ts*132 + 64 + lane] + pb1;
      float s = v0 + v1, qq = v0*v0 + v1*v1;
      red2(s, qq);
      float mu = s * (1.0f/Hh);
      float rstd = rsqrtf(qq * (1.0f/Hh) - mu*mu + 1e-5f);
      float f0 = (v0 - mu)*rstd*gp0 + bp0;
      float f1 = (v1 - mu)*rstd*gp1 + bp1;
      f0 *= fast_rcp(1.0f + fast_ex2(-L2E*f0));
      f1 *= fast_rcp(1.0f + fast_ex2(-L2E*f1));
      feat_s[ts*136 + lane]      = (f16)f0;
      feat_s[ts*136 + 64 + lane] = (f16)f1;
    }
    SYNC();
    {
      half8 bf2[4];
#pragma unroll
      for (int c = 0; c < 4; ++c)
        bf2[c] = *(const half8*)(feat_s + l16*136 + 32*c + 8*q);
      const size_t trow = (size_t)(b*Tt + tl0 + l16) * 512;
      f32x4 accs2[4];
#pragma unroll
      for (int g = 0; g < 4; ++g){
        f32x4 acc = bias2[g];
#pragma unroll
        for (int c = 0; c < 4; ++c)
          acc = MFMA16(aW2[g][c], bf2[c], acc);
        accs2[g] = acc;
      }
      // scan layout store: j = 16wv+4q+r -> [w=wv>>1][l=4q+r][s=wv&1][g]
#pragma unroll
      for (int r = 0; r < 4; ++r){
        U2 u;
#pragma unroll
        for (int g = 0; g < 4; ++g) u.h[g] = (f16)accs2[g][r];
        const int zoff = ((wv>>1)*128) + ((4*q + r)*8) + ((wv&1)*4);
        *(uint2*)(zx + trow + zoff) = u.u;
      }
    }
    SYNC();
  }
}

// ---------------------------------------------------------------------------
// Scan v14 = exact v11 (verified 1899us): 8 waves, wave w8 owns j=16w8+l16,
// 16 MFMA/wave as 8 indep depth-2 chains, z via uint2 + post-MFMA add,
// lgkm-only SYNC, zv prefetch, chunked zbuf staging, h-ring dump.
// (v13's z-fold-into-C and setprio reverted: measured +27us regression.)
// ---------------------------------------------------------------------------
__global__ __launch_bounds__(512, 1)
void scan_k(f16* __restrict__ zx, const float* __restrict__ dt,
            const float* __restrict__ w_ff1, const float* __restrict__ w_ff2,
            const float* __restrict__ w_ta,  const float* __restrict__ w_tb)
{
  __shared__ __align__(16) f16 zbuf[2][CH*512];  // 2 x 16 KB
  __shared__ __align__(16) f16 hist[CH][Hh];     // 4 KB ring of h [16][128]

  const int tid  = threadIdx.x;
  const int w8   = tid >> 6;        // 0..7: j-range [16*w8, 16*w8+16)
  const int lane = tid & 63;
  const int q    = lane >> 4;
  const int l16  = lane & 15;
  const int b    = blockIdx.x;

  const float* Wg[4] = { w_ff1, w_ff2, w_ta, w_tb };

  // B operand = W_bot (k rows 128..255), col jc = 16*w8 + l16
  half8 bW[4][4];                   // [gate][kchunk]
#pragma unroll
  for (int g = 0; g < 4; ++g){
    const float* wp = Wg[g];
    const int jc = 16*w8 + l16;
#pragma unroll
    for (int c = 0; c < 4; ++c)
#pragma unroll
      for (int i = 0; i < 8; ++i)
        bW[g][c][i] = (f16)wp[(128 + 32*c + 8*q + i)*Hh + jc];
  }

  // zero hist ring (slot 15 must be 0 for t=0): 512 thr x 8B = 4 KB
  ((float2*)hist)[tid] = make_float2(0.f, 0.f);

  f16* zg = zx + (size_t)b*Tt*512;
  const float4* zg4 = (const float4*)zg;         // chunk = 1024 float4

  // prologue: chunk0 -> regs -> zbuf[0]; chunk1 -> regs; dt chunk0 -> reg
  float4 rz[2];
  rz[0] = zg4[tid]; rz[1] = zg4[512 + tid];
  ((float4*)zbuf[0])[tid] = rz[0]; ((float4*)zbuf[0])[512 + tid] = rz[1];
  rz[0] = zg4[1024 + tid]; rz[1] = zg4[1536 + tid];
  float dtcur = dt[(size_t)b*Tt + l16] * 10.0f;
  __syncthreads();

  const f32x4 zero4 = {0.f, 0.f, 0.f, 0.f};
  // lane's z slot (f16 elems) in a step row: j=16w8+l16 ->
  // (j>>5)*128 + (j&15)*8 + ((j>>4)&1)*4  (+g)
  const int zoff2 = (w8>>1)*128 + l16*8 + (w8&1)*4;

  for (int c = 0; c < NCH; ++c){
    const int cur = c & 1, nxt = cur ^ 1;
    ((float4*)zbuf[nxt])[tid] = rz[0];
    ((float4*)zbuf[nxt])[512 + tid] = rz[1];
    if (c + 2 < NCH){
      const float4* src = zg4 + (size_t)(c+2)*1024;
      rz[0] = src[tid]; rz[1] = src[512 + tid];
    }
    float dtnxt = dtcur;
    if (c + 1 < NCH) dtnxt = dt[(size_t)b*Tt + (c+1)*CH + l16] * 10.0f;
    const f16* zch = zbuf[cur];

    // zv pipeline prologue: step-0 z (zbuf[cur] written LAST chunk, visible)
    uint2 zv = *(const uint2*)(zch + zoff2);

#pragma unroll
    for (int st = 0; st < CH; ++st){
      const int slotR = (st + 15) & 15;
      // A operand: h broadcast (l16-independent), 4 x b128 — post-barrier path
      half8 af[4];
#pragma unroll
      for (int cc = 0; cc < 4; ++cc)
        af[cc] = *(const half8*)(&hist[slotR][32*cc + 8*q]);
      U2 uz; uz.u = zv;
      const float dtt = rlane(dtcur, st);

      // 8 indep depth-2 chains (4 gates x 2+2 K-split), 16 MFMA/wave
      f32x4 pA[4], pB[4];
#pragma unroll
      for (int g = 0; g < 4; ++g) pA[g] = MFMA16(af[0], bW[g][0], zero4);
#pragma unroll
      for (int g = 0; g < 4; ++g) pB[g] = MFMA16(af[2], bW[g][2], zero4);
#pragma unroll
      for (int g = 0; g < 4; ++g) pA[g] = MFMA16(af[1], bW[g][1], pA[g]);
#pragma unroll
      for (int g = 0; g < 4; ++g) pB[g] = MFMA16(af[3], bW[g][3], pB[g]);

      // prefetch next step's z (zbuf[cur] stable within chunk) before barrier
      if (st + 1 < CH) zv = *(const uint2*)(zch + (st+1)*512 + zoff2);

      // cell for j = 16w8+l16 (q-redundant; q==0 writes)
      float p0 = pA[0][0] + pB[0][0] + (float)uz.h[0];
      float p1 = pA[1][0] + pB[1][0] + (float)uz.h[1];
      float p2 = pA[2][0] + pB[2][0] + (float)uz.h[2];
      float p3 = pA[3][0] + pB[3][0] + (float)uz.h[3];
      float gpre = __builtin_fmaf(p2, dtt, p3);
      float g_ = fast_rcp(fast_ex2(-L2E*gpre) + 1.0f);
      float u_ = fast_rcp(fast_ex2(L2E2*p0) + 1.0f);   // (1-tanh)/2
      float v_ = fast_rcp(fast_ex2(L2E2*p1) + 1.0f);
      float a_ = __builtin_fmaf(-2.0f, u_, 1.0f);
      float hn = __builtin_fmaf(2.0f*g_, u_ - v_, a_);
      if (q == 0)
        hist[st][16*w8 + l16] = (f16)hn;
      SYNC();
    }
    // dump h ring into consumed z region: h[t] -> zg[t*512 + 0..127]
    {
      const uint2 hv2 = ((const uint2*)hist)[tid];
      *(uint2*)(zg + ((size_t)(c*CH + (tid >> 5)))*512 + (size_t)(tid & 31)*4) = hv2;
    }
    SYNC();
    dtcur = dtnxt;
  }
}

// ---------------------------------------------------------------------------
// Head: out[tok] = h[tok] . head_w + head_b (h fp16 from dumped region).
// ---------------------------------------------------------------------------
__global__ __launch_bounds__(256, 4)
void head_k(const f16* __restrict__ zx, const float* __restrict__ head_w,
            const float* __restrict__ head_b, float* __restrict__ out)
{
  const int tok  = (blockIdx.x << 2) + (threadIdx.x >> 6);
  const int lane = threadIdx.x & 63;
  U1 cv; cv.u = *(const unsigned*)(zx + (size_t)tok*512 + 2*lane);
  float s = (float)cv.h[0]*head_w[2*lane] + (float)cv.h[1]*head_w[2*lane+1];
#pragma unroll
  for (int off = 32; off; off >>= 1) s += __shfl_xor(s, off);
  if (lane == 0) out[tok] = s + head_b[0];
}

extern "C" void kernel_launch(void* const* d_in, const int* in_sizes, int n_in,
                              void* d_out, int out_size, void* d_ws, size_t ws_size,
                              hipStream_t stream)
{
  const float* x       = (const float*)d_in[0];
  const float* dt      = (const float*)d_in[1];
  const float* ln_in_g = (const float*)d_in[2];
  const float* ln_in_b = (const float*)d_in[3];
  const float* proj_w  = (const float*)d_in[4];
  const float* proj_b  = (const float*)d_in[5];
  const float* ln_p_g  = (const float*)d_in[6];
  const float* ln_p_b  = (const float*)d_in[7];
  const float* ff1_w   = (const float*)d_in[8];
  const float* ff1_b   = (const float*)d_in[9];
  const float* ff2_w   = (const float*)d_in[10];
  const float* ff2_b   = (const float*)d_in[11];
  const float* ta_w    = (const float*)d_in[12];
  const float* ta_b    = (const float*)d_in[13];
  const float* tb_w    = (const float*)d_in[14];
  const float* tb_b    = (const float*)d_in[15];
  const float* head_w  = (const float*)d_in[16];
  const float* head_b  = (const float*)d_in[17];

  f16*   zx  = (f16*)d_ws;      // [b][t][512] fp16 = 256 MiB (z, then h)
  float* out = (float*)d_out;

  stage_a<<<dim3(512), dim3(512), 0, stream>>>(
      x, ln_in_g, ln_in_b, proj_w, proj_b, ln_p_g, ln_p_b,
      ff1_w, ff1_b, ff2_w, ff2_b, ta_w, ta_b, tb_w, tb_b, zx);

  scan_k<<<dim3(Bb), dim3(512), 0, stream>>>(
      zx, dt, ff1_w, ff2_w, ta_w, tb_w);

  head_k<<<dim3(Bb*Tt/4), dim3(256), 0, stream>>>(
      zx, head_w, head_b, out);
}